// Round 1
// baseline (1327.257 us; speedup 1.0000x reference)
//
#include <hip/hip_runtime.h>
#include <cstdint>
#include <cstddef>

typedef unsigned short u16;
typedef short bf16x8 __attribute__((ext_vector_type(8)));
typedef float f32x4 __attribute__((ext_vector_type(4)));

#define LN_EPS 1e-6f

__device__ inline u16 f2bf(float f) {
    uint32_t x = __float_as_uint(f);
    uint32_t r = (x + 0x7fffu + ((x >> 16) & 1u)) >> 16;   // RNE
    return (u16)r;
}
__device__ inline float bf2f(u16 u) { return __uint_as_float(((uint32_t)u) << 16); }

// ---------------- block reductions (256 threads = 4 waves) ----------------
__device__ inline float blk_sum(float v, float* s) {
    #pragma unroll
    for (int o = 32; o > 0; o >>= 1) v += __shfl_xor(v, o);
    __syncthreads();
    if ((threadIdx.x & 63) == 0) s[threadIdx.x >> 6] = v;
    __syncthreads();
    return s[0] + s[1] + s[2] + s[3];
}
__device__ inline float blk_max(float v, float* s) {
    #pragma unroll
    for (int o = 32; o > 0; o >>= 1) v = fmaxf(v, __shfl_xor(v, o));
    __syncthreads();
    if ((threadIdx.x & 63) == 0) s[threadIdx.x >> 6] = v;
    __syncthreads();
    return fmaxf(fmaxf(s[0], s[1]), fmaxf(s[2], s[3]));
}

// ---------------- GEMM: C[m][n] = sum_k A[m][k] * B[n][k]  (both row-major, k-contiguous)
// MODE: 0 = f32 store (scale), 1 = f32 relu(acc+bias), 2 = f32 += relu(acc+bias),
//       3 = bf16 store (scale), 4 = bf16 split hi/lo store (scale)
// SPLIT: A = Ah+Al, B = Bh+Bl, acc += Ah*Bh + Al*Bh + Ah*Bl  (drop Al*Bl)
template<bool SPLIT, int MODE>
__global__ __launch_bounds__(256) void gemm_k(
    const u16* __restrict__ A, const u16* __restrict__ Al,
    const u16* __restrict__ B, const u16* __restrict__ Bl,
    float* __restrict__ Cf, u16* __restrict__ Cb, u16* __restrict__ Cb2,
    const float* __restrict__ bias,
    int M, int N, int K, int ldc, float scale)
{
    constexpr int LDP = 40;                 // padded row (80B, 16B-aligned)
    __shared__ u16 sA[128][LDP];
    __shared__ u16 sB[128][LDP];
    __shared__ u16 sAl[SPLIT ? 128 : 1][SPLIT ? LDP : 1];
    __shared__ u16 sBl[SPLIT ? 128 : 1][SPLIT ? LDP : 1];

    const int tid  = threadIdx.x;
    const int lane = tid & 63;
    const int wid  = tid >> 6;
    const int wr = wid >> 1, wc = wid & 1;  // 2x2 waves, 64x64 each
    const int fr = lane & 15;               // row/col within 16
    const int fg = lane >> 4;               // k-group
    const int m0 = blockIdx.y * 128, n0 = blockIdx.x * 128;

    f32x4 acc[4][4];
    {
        f32x4 z = {0.f, 0.f, 0.f, 0.f};
        #pragma unroll
        for (int i = 0; i < 4; i++)
            #pragma unroll
            for (int j = 0; j < 4; j++) acc[i][j] = z;
    }

    for (int k0 = 0; k0 < K; k0 += 32) {
        #pragma unroll
        for (int p = 0; p < 2; ++p) {
            int q = p * 256 + tid;
            int row = q >> 2, c = q & 3;
            *reinterpret_cast<int4*>(&sA[row][c * 8]) =
                *(reinterpret_cast<const int4*>(A + (size_t)(m0 + row) * K + k0) + c);
            *reinterpret_cast<int4*>(&sB[row][c * 8]) =
                *(reinterpret_cast<const int4*>(B + (size_t)(n0 + row) * K + k0) + c);
            if constexpr (SPLIT) {
                *reinterpret_cast<int4*>(&sAl[row][c * 8]) =
                    *(reinterpret_cast<const int4*>(Al + (size_t)(m0 + row) * K + k0) + c);
                *reinterpret_cast<int4*>(&sBl[row][c * 8]) =
                    *(reinterpret_cast<const int4*>(Bl + (size_t)(n0 + row) * K + k0) + c);
            }
        }
        __syncthreads();

        bf16x8 av[4], bv[4], avl[4], bvl[4];
        #pragma unroll
        for (int f = 0; f < 4; ++f) {
            av[f] = *reinterpret_cast<const bf16x8*>(&sA[wr * 64 + f * 16 + fr][fg * 8]);
            bv[f] = *reinterpret_cast<const bf16x8*>(&sB[wc * 64 + f * 16 + fr][fg * 8]);
            if constexpr (SPLIT) {
                avl[f] = *reinterpret_cast<const bf16x8*>(&sAl[wr * 64 + f * 16 + fr][fg * 8]);
                bvl[f] = *reinterpret_cast<const bf16x8*>(&sBl[wc * 64 + f * 16 + fr][fg * 8]);
            }
        }
        #pragma unroll
        for (int i = 0; i < 4; i++)
            #pragma unroll
            for (int j = 0; j < 4; j++) {
                acc[i][j] = __builtin_amdgcn_mfma_f32_16x16x32_bf16(av[i], bv[j], acc[i][j], 0, 0, 0);
                if constexpr (SPLIT) {
                    acc[i][j] = __builtin_amdgcn_mfma_f32_16x16x32_bf16(avl[i], bv[j], acc[i][j], 0, 0, 0);
                    acc[i][j] = __builtin_amdgcn_mfma_f32_16x16x32_bf16(av[i], bvl[j], acc[i][j], 0, 0, 0);
                }
            }
        __syncthreads();
    }

    // epilogue: D layout col = lane&15, row = (lane>>4)*4 + reg   [HW-verified]
    #pragma unroll
    for (int i = 0; i < 4; i++)
        #pragma unroll
        for (int j = 0; j < 4; j++)
            #pragma unroll
            for (int r = 0; r < 4; r++) {
                int row = m0 + wr * 64 + i * 16 + fg * 4 + r;
                int col = n0 + wc * 64 + j * 16 + fr;
                float v = acc[i][j][r] * scale;
                size_t idx = (size_t)row * ldc + col;
                if (MODE == 0) {
                    Cf[idx] = v;
                } else if (MODE == 1) {
                    Cf[idx] = fmaxf(v + bias[col], 0.f);
                } else if (MODE == 2) {
                    Cf[idx] += fmaxf(v + bias[col], 0.f);
                } else if (MODE == 3) {
                    Cb[idx] = f2bf(v);
                } else {
                    u16 h = f2bf(v);
                    Cb[idx]  = h;
                    Cb2[idx] = f2bf(v - bf2f(h));
                }
            }
}

// ---------------- elementwise / converts ----------------
__global__ __launch_bounds__(256) void split_k(const float* __restrict__ s,
                                               u16* __restrict__ hi, u16* __restrict__ lo) {
    int i = blockIdx.x * 256 + threadIdx.x;
    const float4* sf = reinterpret_cast<const float4*>(s);
    float4 a = sf[2 * i], b = sf[2 * i + 1];
    float vals[8] = {a.x, a.y, a.z, a.w, b.x, b.y, b.z, b.w};
    union { u16 u[8]; int4 v; } th, tl;
    #pragma unroll
    for (int k = 0; k < 8; k++) {
        u16 h = f2bf(vals[k]);
        th.u[k] = h;
        tl.u[k] = f2bf(vals[k] - bf2f(h));
    }
    reinterpret_cast<int4*>(hi)[i] = th.v;
    reinterpret_cast<int4*>(lo)[i] = tl.v;
}

__global__ __launch_bounds__(256) void cvt_k(const float* __restrict__ s, u16* __restrict__ d) {
    int i = blockIdx.x * 256 + threadIdx.x;
    const float4* sf = reinterpret_cast<const float4*>(s);
    float4 a = sf[2 * i], b = sf[2 * i + 1];
    union { u16 u[8]; int4 v; } t;
    t.u[0] = f2bf(a.x); t.u[1] = f2bf(a.y); t.u[2] = f2bf(a.z); t.u[3] = f2bf(a.w);
    t.u[4] = f2bf(b.x); t.u[5] = f2bf(b.y); t.u[6] = f2bf(b.z); t.u[7] = f2bf(b.w);
    reinterpret_cast<int4*>(d)[i] = t.v;
}

// dbuf[i][:] = bf16(|x[i+shift][:] - x[i][:]|) for i<8188, else 0
__global__ __launch_bounds__(256) void diff_k(const float* __restrict__ x, u16* __restrict__ d, int shift) {
    int i4 = blockIdx.x * 256 + threadIdx.x;    // float4 index; 256 per row
    int row = i4 >> 8;
    const float4* xf = reinterpret_cast<const float4*>(x);
    ushort4 o;
    if (row < 8188) {
        float4 a = xf[i4 + (shift << 8)];
        float4 b = xf[i4];
        o.x = f2bf(fabsf(a.x - b.x));
        o.y = f2bf(fabsf(a.y - b.y));
        o.z = f2bf(fabsf(a.z - b.z));
        o.w = f2bf(fabsf(a.w - b.w));
    } else {
        o.x = o.y = o.z = o.w = 0;
    }
    reinterpret_cast<ushort4*>(d)[i4] = o;
}

__global__ __launch_bounds__(256) void tail_k(const float* __restrict__ x, float* __restrict__ mn) {
    int i = blockIdx.x * 256 + threadIdx.x;     // 4096 elems: rows 8188..8191
    mn[8188 * 1024 + i] = x[8188 * 1024 + i];
}

// ---------------- softmax over a row of 8192 fp32 ----------------
__global__ __launch_bounds__(256) void softmax_k(const float* __restrict__ S,
                                                 float* __restrict__ aw, int row0) {
    __shared__ float red[4];
    int r = blockIdx.x, tid = threadIdx.x;
    const float4* src = reinterpret_cast<const float4*>(S + (size_t)r * 8192);
    float4 xv[8];
    float mx = -1e30f;
    #pragma unroll
    for (int j = 0; j < 8; j++) {
        xv[j] = src[tid + 256 * j];
        mx = fmaxf(mx, fmaxf(fmaxf(xv[j].x, xv[j].y), fmaxf(xv[j].z, xv[j].w)));
    }
    mx = blk_max(mx, red);
    float sum = 0.f;
    #pragma unroll
    for (int j = 0; j < 8; j++) {
        xv[j].x = __expf(xv[j].x - mx); sum += xv[j].x;
        xv[j].y = __expf(xv[j].y - mx); sum += xv[j].y;
        xv[j].z = __expf(xv[j].z - mx); sum += xv[j].z;
        xv[j].w = __expf(xv[j].w - mx); sum += xv[j].w;
    }
    sum = blk_sum(sum, red);
    float inv = 1.0f / sum;
    float4* dst = reinterpret_cast<float4*>(aw + (size_t)(row0 + r) * 8192);
    #pragma unroll
    for (int j = 0; j < 8; j++) {
        float4 o;
        o.x = xv[j].x * inv; o.y = xv[j].y * inv; o.z = xv[j].z * inv; o.w = xv[j].w * inv;
        dst[tid + 256 * j] = o;
    }
}

// ---------------- transposes (64x64 tiles) ----------------
// aw (8192x8192 fp32) -> ST (8192x8192 bf16), ST[i][k] = aw[k][i]
__global__ __launch_bounds__(256) void transpose_f32_bf16(const float* __restrict__ src,
                                                          u16* __restrict__ dst) {
    __shared__ u16 t[64][72];
    int r0 = blockIdx.y * 64, c0 = blockIdx.x * 64;
    int tid = threadIdx.x;
    #pragma unroll
    for (int p = 0; p < 4; p++) {
        int q = p * 256 + tid;
        int r = q >> 4, c4 = q & 15;
        float4 v = *(reinterpret_cast<const float4*>(src + (size_t)(r0 + r) * 8192 + c0) + c4);
        t[c4 * 4 + 0][r] = f2bf(v.x);
        t[c4 * 4 + 1][r] = f2bf(v.y);
        t[c4 * 4 + 2][r] = f2bf(v.z);
        t[c4 * 4 + 3][r] = f2bf(v.w);
    }
    __syncthreads();
    #pragma unroll
    for (int p = 0; p < 2; p++) {
        int q = p * 256 + tid;
        int rr = q >> 3, cc = q & 7;
        *reinterpret_cast<int4*>(dst + (size_t)(c0 + rr) * 8192 + r0 + cc * 8) =
            *reinterpret_cast<const int4*>(&t[rr][cc * 8]);
    }
}

// bf16 (srows x scols) -> bf16 (scols x srows)
__global__ __launch_bounds__(256) void transpose_bf16(const u16* __restrict__ src,
                                                      u16* __restrict__ dst,
                                                      int srows, int scols) {
    __shared__ u16 t[64][72];
    int r0 = blockIdx.y * 64, c0 = blockIdx.x * 64;
    int tid = threadIdx.x;
    #pragma unroll
    for (int p = 0; p < 2; p++) {
        int q = p * 256 + tid;
        int r = q >> 3, c8 = q & 7;
        int4 v = *(reinterpret_cast<const int4*>(src + (size_t)(r0 + r) * scols + c0) + c8);
        const u16* u = reinterpret_cast<const u16*>(&v);
        #pragma unroll
        for (int k = 0; k < 8; k++) t[c8 * 8 + k][r] = u[k];
    }
    __syncthreads();
    #pragma unroll
    for (int p = 0; p < 2; p++) {
        int q = p * 256 + tid;
        int rr = q >> 3, cc = q & 7;
        *reinterpret_cast<int4*>(dst + (size_t)(c0 + rr) * srows + r0 + cc * 8) =
            *reinterpret_cast<const int4*>(&t[rr][cc * 8]);
    }
}

// ---------------- LN kernels ----------------
__global__ __launch_bounds__(256) void ln_y_k(const float* __restrict__ y2, const float* __restrict__ mn,
                                              const float* __restrict__ g, const float* __restrict__ b,
                                              u16* __restrict__ zb) {
    __shared__ float red[4];
    int r = blockIdx.x, tid = threadIdx.x;
    float4 a = reinterpret_cast<const float4*>(y2 + (size_t)r * 1024)[tid];
    float4 c = reinterpret_cast<const float4*>(mn + (size_t)r * 1024)[tid];
    float4 v; v.x = a.x + c.x; v.y = a.y + c.y; v.z = a.z + c.z; v.w = a.w + c.w;
    float s  = v.x + v.y + v.z + v.w;
    float sq = v.x * v.x + v.y * v.y + v.z * v.z + v.w * v.w;
    s  = blk_sum(s, red);
    sq = blk_sum(sq, red);
    float mu = s * (1.0f / 1024.0f);
    float rs = rsqrtf(sq * (1.0f / 1024.0f) - mu * mu + LN_EPS);
    float4 gg = reinterpret_cast<const float4*>(g)[tid];
    float4 bb = reinterpret_cast<const float4*>(b)[tid];
    ushort4 o;
    o.x = f2bf((v.x - mu) * rs * gg.x + bb.x);
    o.y = f2bf((v.y - mu) * rs * gg.y + bb.y);
    o.z = f2bf((v.z - mu) * rs * gg.z + bb.z);
    o.w = f2bf((v.w - mu) * rs * gg.w + bb.w);
    reinterpret_cast<ushort4*>(zb + (size_t)r * 1024)[tid] = o;
}

__global__ __launch_bounds__(256) void ln_dot_k(const float* __restrict__ h, const float* __restrict__ g,
                                                const float* __restrict__ b, const float* __restrict__ kd,
                                                const float* __restrict__ kdb, float* __restrict__ out) {
    __shared__ float red[4];
    int r = blockIdx.x, tid = threadIdx.x;
    float4 v = reinterpret_cast<const float4*>(h + (size_t)r * 1024)[tid];
    float s  = v.x + v.y + v.z + v.w;
    float sq = v.x * v.x + v.y * v.y + v.z * v.z + v.w * v.w;
    s  = blk_sum(s, red);
    sq = blk_sum(sq, red);
    float mu = s * (1.0f / 1024.0f);
    float rs = rsqrtf(sq * (1.0f / 1024.0f) - mu * mu + LN_EPS);
    float4 gg = reinterpret_cast<const float4*>(g)[tid];
    float4 bb = reinterpret_cast<const float4*>(b)[tid];
    float4 kk = reinterpret_cast<const float4*>(kd)[tid];
    float part = ((v.x - mu) * rs * gg.x + bb.x) * kk.x
               + ((v.y - mu) * rs * gg.y + bb.y) * kk.y
               + ((v.z - mu) * rs * gg.z + bb.z) * kk.z
               + ((v.w - mu) * rs * gg.w + bb.w) * kk.w;
    part = blk_sum(part, red);
    if (tid == 0) out[r] = 1.0f / (1.0f + __expf(-(part + kdb[0])));
}

// ---------------- launch ----------------
extern "C" void kernel_launch(void* const* d_in, const int* in_sizes, int n_in,
                              void* d_out, int out_size, void* d_ws, size_t ws_size,
                              hipStream_t stream) {
    (void)in_sizes; (void)n_in; (void)out_size; (void)ws_size;
    const float* x    = (const float*)d_in[0];
    const float* Wq   = (const float*)d_in[2];
    const float* Wk   = (const float*)d_in[3];
    const float* Wv   = (const float*)d_in[4];
    const float* Wo   = (const float*)d_in[5];
    const float* fc1w = (const float*)d_in[6];
    const float* fc1b = (const float*)d_in[7];
    const float* kaw  = (const float*)d_in[8];
    const float* kab  = (const float*)d_in[9];
    const float* kdw  = (const float*)d_in[10];
    const float* kdb  = (const float*)d_in[11];
    const float* lyg  = (const float*)d_in[12];
    const float* lyb  = (const float*)d_in[13];
    const float* lkg  = (const float*)d_in[14];
    const float* lkb  = (const float*)d_in[15];

    float* out0 = (float*)d_out;
    float* aw   = out0 + 8192;

    char* base = (char*)d_ws;
    size_t off = 0;
    auto alloc = [&](size_t bytes) -> char* {
        char* p = base + off;
        off += (bytes + 255) & ~(size_t)255;
        return p;
    };
    const size_t NM = 8192ULL * 1024ULL;           // 8,388,608
    u16*   ST   = (u16*)alloc(8192ULL * 8192ULL * 2);   // 128MB; first 64MB doubles as Sf
    float* Sf   = (float*)ST;                           // 2048 x 8192 fp32 chunk
    u16*   xh   = (u16*)alloc(NM * 2);
    u16*   xl   = (u16*)alloc(NM * 2);
    u16*   qh   = (u16*)alloc(NM * 2);
    u16*   ql   = (u16*)alloc(NM * 2);
    u16*   kh   = (u16*)alloc(NM * 2);
    u16*   kl   = (u16*)alloc(NM * 2);
    u16*   Vb   = (u16*)alloc(NM * 2);
    u16*   Vt   = (u16*)alloc(NM * 2);
    u16*   dbuf = (u16*)alloc(NM * 2);                  // later reused as zb
    u16*   yb   = (u16*)alloc(NM * 2);
    float* mn   = (float*)alloc(NM * 4);
    float* y    = (float*)alloc(NM * 4);                // later reused as h
    float* y2   = (float*)alloc(NM * 4);
    u16*   Wqh  = (u16*)alloc(1048576ULL * 2);
    u16*   Wql  = (u16*)alloc(1048576ULL * 2);
    u16*   Wkh  = (u16*)alloc(1048576ULL * 2);
    u16*   Wkl  = (u16*)alloc(1048576ULL * 2);
    u16*   Wvb  = (u16*)alloc(1048576ULL * 2);
    u16*   Wob  = (u16*)alloc(1048576ULL * 2);
    u16*   fwb  = (u16*)alloc(1048576ULL * 2);
    u16*   kwb  = (u16*)alloc(1048576ULL * 2);
    u16*   zb   = dbuf;
    float* hbuf = y;

    // 1) converts / splits
    split_k<<<4096, 256, 0, stream>>>(x, xh, xl);
    split_k<<<512, 256, 0, stream>>>(Wq, Wqh, Wql);
    split_k<<<512, 256, 0, stream>>>(Wk, Wkh, Wkl);
    cvt_k<<<512, 256, 0, stream>>>(Wv, Wvb);
    cvt_k<<<512, 256, 0, stream>>>(Wo, Wob);
    cvt_k<<<512, 256, 0, stream>>>(fc1w, fwb);
    cvt_k<<<512, 256, 0, stream>>>(kaw, kwb);

    // 2) mn = relu(d1@fc1^T+b) + relu(d2@..) + relu(d3@..); tail rows = x
    diff_k<<<8192, 256, 0, stream>>>(x, dbuf, 1);
    gemm_k<false, 1><<<dim3(8, 64), 256, 0, stream>>>(dbuf, nullptr, fwb, nullptr,
        mn, nullptr, nullptr, fc1b, 8192, 1024, 1024, 1024, 1.0f);
    diff_k<<<8192, 256, 0, stream>>>(x, dbuf, 2);
    gemm_k<false, 2><<<dim3(8, 64), 256, 0, stream>>>(dbuf, nullptr, fwb, nullptr,
        mn, nullptr, nullptr, fc1b, 8192, 1024, 1024, 1024, 1.0f);
    diff_k<<<8192, 256, 0, stream>>>(x, dbuf, 4);
    gemm_k<false, 2><<<dim3(8, 64), 256, 0, stream>>>(dbuf, nullptr, fwb, nullptr,
        mn, nullptr, nullptr, fc1b, 8192, 1024, 1024, 1024, 1.0f);
    tail_k<<<16, 256, 0, stream>>>(x, mn);

    // 3) Q (split, x0.06), K (split), V (plain)
    gemm_k<true, 4><<<dim3(8, 64), 256, 0, stream>>>(xh, xl, Wqh, Wql,
        nullptr, qh, ql, nullptr, 8192, 1024, 1024, 1024, 0.06f);
    gemm_k<true, 4><<<dim3(8, 64), 256, 0, stream>>>(xh, xl, Wkh, Wkl,
        nullptr, kh, kl, nullptr, 8192, 1024, 1024, 1024, 1.0f);
    gemm_k<false, 3><<<dim3(8, 64), 256, 0, stream>>>(xh, nullptr, Wvb, nullptr,
        nullptr, Vb, nullptr, nullptr, 8192, 1024, 1024, 1024, 1.0f);
    transpose_bf16<<<dim3(16, 128), 256, 0, stream>>>(Vb, Vt, 8192, 1024);

    // 4) logits (split, fp32) + softmax, 4 chunks of 2048 rows; aw -> d_out
    for (int c = 0; c < 4; ++c) {
        gemm_k<true, 0><<<dim3(64, 16), 256, 0, stream>>>(
            qh + (size_t)c * 2048 * 1024, ql + (size_t)c * 2048 * 1024, kh, kl,
            Sf, nullptr, nullptr, nullptr, 2048, 8192, 1024, 8192, 1.0f);
        softmax_k<<<2048, 256, 0, stream>>>(Sf, aw, c * 2048);
    }

    // 5) ST = aw^T (bf16), y = ST @ Vt^T  (== aw^T @ V)
    transpose_f32_bf16<<<dim3(128, 128), 256, 0, stream>>>(aw, ST);
    gemm_k<false, 0><<<dim3(8, 64), 256, 0, stream>>>(ST, nullptr, Vt, nullptr,
        y, nullptr, nullptr, nullptr, 8192, 1024, 8192, 1024, 1.0f);

    // 6) y2 = y @ Wo^T ; z = LN(y2+mn) ; h = relu(z@ka^T+b) ; out = sigmoid(LN(h)@kd^T+kdb)
    cvt_k<<<4096, 256, 0, stream>>>(y, yb);
    gemm_k<false, 0><<<dim3(8, 64), 256, 0, stream>>>(yb, nullptr, Wob, nullptr,
        y2, nullptr, nullptr, nullptr, 8192, 1024, 1024, 1024, 1.0f);
    ln_y_k<<<8192, 256, 0, stream>>>(y2, mn, lyg, lyb, zb);
    gemm_k<false, 1><<<dim3(8, 64), 256, 0, stream>>>(zb, nullptr, kwb, nullptr,
        hbuf, nullptr, nullptr, kab, 8192, 1024, 1024, 1024, 1.0f);
    ln_dot_k<<<8192, 256, 0, stream>>>(hbuf, lkg, lkb, kdw, kdb, out0);
}

// Round 2
// 1307.045 us; speedup vs baseline: 1.0155x; 1.0155x over previous
//
#include <hip/hip_runtime.h>
#include <cstdint>
#include <cstddef>

typedef unsigned short u16;
typedef short bf16x8 __attribute__((ext_vector_type(8)));
typedef float f32x4 __attribute__((ext_vector_type(4)));

#define LN_EPS 1e-6f

// async global->LDS, 16B per lane; LDS dest is wave-uniform base + lane*16
#define GLD16(gsrc, ldst) \
    __builtin_amdgcn_global_load_lds( \
        (const __attribute__((address_space(1))) void*)(gsrc), \
        (__attribute__((address_space(3))) void*)(ldst), 16, 0, 0)

__device__ inline u16 f2bf(float f) {
    uint32_t x = __float_as_uint(f);
    uint32_t r = (x + 0x7fffu + ((x >> 16) & 1u)) >> 16;   // RNE
    return (u16)r;
}
__device__ inline float bf2f(u16 u) { return __uint_as_float(((uint32_t)u) << 16); }

// ---------------- block reductions (256 threads = 4 waves) ----------------
__device__ inline float blk_sum(float v, float* s) {
    #pragma unroll
    for (int o = 32; o > 0; o >>= 1) v += __shfl_xor(v, o);
    __syncthreads();
    if ((threadIdx.x & 63) == 0) s[threadIdx.x >> 6] = v;
    __syncthreads();
    return s[0] + s[1] + s[2] + s[3];
}
__device__ inline float blk_max(float v, float* s) {
    #pragma unroll
    for (int o = 32; o > 0; o >>= 1) v = fmaxf(v, __shfl_xor(v, o));
    __syncthreads();
    if ((threadIdx.x & 63) == 0) s[threadIdx.x >> 6] = v;
    __syncthreads();
    return fmaxf(fmaxf(s[0], s[1]), fmaxf(s[2], s[3]));
}

// ---------------- GEMM: C[m][n] = sum_k A[m][k] * B[n][k]  (both row-major, k-contiguous)
// MODE: 0 = f32 store (scale), 1 = f32 relu(acc+bias), 2 = f32 += relu(acc+bias),
//       3 = bf16 store (scale), 4 = bf16 split hi/lo store (scale)
// SPLIT: A = Ah+Al, B = Bh+Bl, acc += Ah*Bh + Al*Bh + Ah*Bl  (drop Al*Bl)
// Staging: global_load_lds width-16, linear LDS [128][32] bf16 (m97 pattern).
// Block swizzle: bijective XCD remap — REQUIRES gridDim.x*gridDim.y % 8 == 0.
template<bool SPLIT, int MODE>
__global__ __launch_bounds__(256) void gemm_k(
    const u16* __restrict__ A, const u16* __restrict__ Al,
    const u16* __restrict__ B, const u16* __restrict__ Bl,
    float* __restrict__ Cf, u16* __restrict__ Cb, u16* __restrict__ Cb2,
    const float* __restrict__ bias,
    int M, int N, int K, int ldc, float scale)
{
    __shared__ u16 sA[128 * 32];
    __shared__ u16 sB[128 * 32];
    __shared__ u16 sAl[SPLIT ? 128 * 32 : 8];
    __shared__ u16 sBl[SPLIT ? 128 * 32 : 8];

    const int tid  = threadIdx.x;
    const int lane = tid & 63;
    const int wid  = tid >> 6;
    const int wr = wid >> 1, wc = wid & 1;  // 2x2 waves, 64x64 each
    const int fr = lane & 15;               // row/col within 16
    const int fg = lane >> 4;               // k-group

    // XCD-aware swizzle: XCD k owns contiguous wg range [k*nwg/8, (k+1)*nwg/8)
    const int gx = gridDim.x;
    const int nwg = gx * gridDim.y;
    const int bid = blockIdx.y * gx + blockIdx.x;
    const int wg  = (bid & 7) * (nwg >> 3) + (bid >> 3);
    const int m0 = (wg / gx) * 128, n0 = (wg % gx) * 128;

    f32x4 acc[4][4];
    {
        f32x4 z = {0.f, 0.f, 0.f, 0.f};
        #pragma unroll
        for (int i = 0; i < 4; i++)
            #pragma unroll
            for (int j = 0; j < 4; j++) acc[i][j] = z;
    }

    for (int k0 = 0; k0 < K; k0 += 32) {
        // stage 128x32 bf16 tiles: 8 KB each = 8 wave-chunks of 1024 B
        #pragma unroll
        for (int c2 = 0; c2 < 2; ++c2) {
            int c    = wid * 2 + c2;            // wave-uniform chunk 0..7
            int boff = c * 1024 + lane * 16;    // byte offset in tile
            int row  = boff >> 6;               // 64 B per row
            int kb   = (boff & 63) >> 1;        // bf16 index within row
            size_t ga = (size_t)(m0 + row) * K + (k0 + kb);
            size_t gb = (size_t)(n0 + row) * K + (k0 + kb);
            GLD16(A + ga, &sA[c * 512]);
            GLD16(B + gb, &sB[c * 512]);
            if constexpr (SPLIT) {
                GLD16(Al + ga, &sAl[c * 512]);
                GLD16(Bl + gb, &sBl[c * 512]);
            }
        }
        __syncthreads();

        bf16x8 av[4], bv[4], avl[4], bvl[4];
        #pragma unroll
        for (int f = 0; f < 4; ++f) {
            av[f] = *reinterpret_cast<const bf16x8*>(&sA[(wr * 64 + f * 16 + fr) * 32 + fg * 8]);
            bv[f] = *reinterpret_cast<const bf16x8*>(&sB[(wc * 64 + f * 16 + fr) * 32 + fg * 8]);
            if constexpr (SPLIT) {
                avl[f] = *reinterpret_cast<const bf16x8*>(&sAl[(wr * 64 + f * 16 + fr) * 32 + fg * 8]);
                bvl[f] = *reinterpret_cast<const bf16x8*>(&sBl[(wc * 64 + f * 16 + fr) * 32 + fg * 8]);
            }
        }
        #pragma unroll
        for (int i = 0; i < 4; i++)
            #pragma unroll
            for (int j = 0; j < 4; j++) {
                acc[i][j] = __builtin_amdgcn_mfma_f32_16x16x32_bf16(av[i], bv[j], acc[i][j], 0, 0, 0);
                if constexpr (SPLIT) {
                    acc[i][j] = __builtin_amdgcn_mfma_f32_16x16x32_bf16(avl[i], bv[j], acc[i][j], 0, 0, 0);
                    acc[i][j] = __builtin_amdgcn_mfma_f32_16x16x32_bf16(av[i], bvl[j], acc[i][j], 0, 0, 0);
                }
            }
        __syncthreads();
    }

    // epilogue: D layout col = lane&15, row = (lane>>4)*4 + reg   [HW-verified]
    #pragma unroll
    for (int i = 0; i < 4; i++)
        #pragma unroll
        for (int j = 0; j < 4; j++)
            #pragma unroll
            for (int r = 0; r < 4; r++) {
                int row = m0 + wr * 64 + i * 16 + fg * 4 + r;
                int col = n0 + wc * 64 + j * 16 + fr;
                float v = acc[i][j][r] * scale;
                size_t idx = (size_t)row * ldc + col;
                if (MODE == 0) {
                    Cf[idx] = v;
                } else if (MODE == 1) {
                    Cf[idx] = fmaxf(v + bias[col], 0.f);
                } else if (MODE == 2) {
                    Cf[idx] += fmaxf(v + bias[col], 0.f);
                } else if (MODE == 3) {
                    Cb[idx] = f2bf(v);
                } else {
                    u16 h = f2bf(v);
                    Cb[idx]  = h;
                    Cb2[idx] = f2bf(v - bf2f(h));
                }
            }
}

// ---------------- elementwise / converts ----------------
__global__ __launch_bounds__(256) void split_k(const float* __restrict__ s,
                                               u16* __restrict__ hi, u16* __restrict__ lo) {
    int i = blockIdx.x * 256 + threadIdx.x;
    const float4* sf = reinterpret_cast<const float4*>(s);
    float4 a = sf[2 * i], b = sf[2 * i + 1];
    float vals[8] = {a.x, a.y, a.z, a.w, b.x, b.y, b.z, b.w};
    union { u16 u[8]; int4 v; } th, tl;
    #pragma unroll
    for (int k = 0; k < 8; k++) {
        u16 h = f2bf(vals[k]);
        th.u[k] = h;
        tl.u[k] = f2bf(vals[k] - bf2f(h));
    }
    reinterpret_cast<int4*>(hi)[i] = th.v;
    reinterpret_cast<int4*>(lo)[i] = tl.v;
}

__global__ __launch_bounds__(256) void cvt_k(const float* __restrict__ s, u16* __restrict__ d) {
    int i = blockIdx.x * 256 + threadIdx.x;
    const float4* sf = reinterpret_cast<const float4*>(s);
    float4 a = sf[2 * i], b = sf[2 * i + 1];
    union { u16 u[8]; int4 v; } t;
    t.u[0] = f2bf(a.x); t.u[1] = f2bf(a.y); t.u[2] = f2bf(a.z); t.u[3] = f2bf(a.w);
    t.u[4] = f2bf(b.x); t.u[5] = f2bf(b.y); t.u[6] = f2bf(b.z); t.u[7] = f2bf(b.w);
    reinterpret_cast<int4*>(d)[i] = t.v;
}

// dbuf[i][:] = bf16(|x[i+shift][:] - x[i][:]|) for i<8188, else 0
__global__ __launch_bounds__(256) void diff_k(const float* __restrict__ x, u16* __restrict__ d, int shift) {
    int i4 = blockIdx.x * 256 + threadIdx.x;    // float4 index; 256 per row
    int row = i4 >> 8;
    const float4* xf = reinterpret_cast<const float4*>(x);
    ushort4 o;
    if (row < 8188) {
        float4 a = xf[i4 + (shift << 8)];
        float4 b = xf[i4];
        o.x = f2bf(fabsf(a.x - b.x));
        o.y = f2bf(fabsf(a.y - b.y));
        o.z = f2bf(fabsf(a.z - b.z));
        o.w = f2bf(fabsf(a.w - b.w));
    } else {
        o.x = o.y = o.z = o.w = 0;
    }
    reinterpret_cast<ushort4*>(d)[i4] = o;
}

__global__ __launch_bounds__(256) void tail_k(const float* __restrict__ x, float* __restrict__ mn) {
    int i = blockIdx.x * 256 + threadIdx.x;     // 4096 elems: rows 8188..8191
    mn[8188 * 1024 + i] = x[8188 * 1024 + i];
}

// ---------------- softmax over a row of 8192 fp32 ----------------
__global__ __launch_bounds__(256) void softmax_k(const float* __restrict__ S,
                                                 float* __restrict__ aw, int row0) {
    __shared__ float red[4];
    int r = blockIdx.x, tid = threadIdx.x;
    const float4* src = reinterpret_cast<const float4*>(S + (size_t)r * 8192);
    float4 xv[8];
    float mx = -1e30f;
    #pragma unroll
    for (int j = 0; j < 8; j++) {
        xv[j] = src[tid + 256 * j];
        mx = fmaxf(mx, fmaxf(fmaxf(xv[j].x, xv[j].y), fmaxf(xv[j].z, xv[j].w)));
    }
    mx = blk_max(mx, red);
    float sum = 0.f;
    #pragma unroll
    for (int j = 0; j < 8; j++) {
        xv[j].x = __expf(xv[j].x - mx); sum += xv[j].x;
        xv[j].y = __expf(xv[j].y - mx); sum += xv[j].y;
        xv[j].z = __expf(xv[j].z - mx); sum += xv[j].z;
        xv[j].w = __expf(xv[j].w - mx); sum += xv[j].w;
    }
    sum = blk_sum(sum, red);
    float inv = 1.0f / sum;
    float4* dst = reinterpret_cast<float4*>(aw + (size_t)(row0 + r) * 8192);
    #pragma unroll
    for (int j = 0; j < 8; j++) {
        float4 o;
        o.x = xv[j].x * inv; o.y = xv[j].y * inv; o.z = xv[j].z * inv; o.w = xv[j].w * inv;
        dst[tid + 256 * j] = o;
    }
}

// ---------------- transposes (64x64 tiles) ----------------
// aw (8192x8192 fp32) -> ST (8192x8192 bf16), ST[i][k] = aw[k][i]
__global__ __launch_bounds__(256) void transpose_f32_bf16(const float* __restrict__ src,
                                                          u16* __restrict__ dst) {
    __shared__ u16 t[64][72];
    int r0 = blockIdx.y * 64, c0 = blockIdx.x * 64;
    int tid = threadIdx.x;
    #pragma unroll
    for (int p = 0; p < 4; p++) {
        int q = p * 256 + tid;
        int r = q >> 4, c4 = q & 15;
        float4 v = *(reinterpret_cast<const float4*>(src + (size_t)(r0 + r) * 8192 + c0) + c4);
        t[c4 * 4 + 0][r] = f2bf(v.x);
        t[c4 * 4 + 1][r] = f2bf(v.y);
        t[c4 * 4 + 2][r] = f2bf(v.z);
        t[c4 * 4 + 3][r] = f2bf(v.w);
    }
    __syncthreads();
    #pragma unroll
    for (int p = 0; p < 2; p++) {
        int q = p * 256 + tid;
        int rr = q >> 3, cc = q & 7;
        *reinterpret_cast<int4*>(dst + (size_t)(c0 + rr) * 8192 + r0 + cc * 8) =
            *reinterpret_cast<const int4*>(&t[rr][cc * 8]);
    }
}

// bf16 (srows x scols) -> bf16 (scols x srows)
__global__ __launch_bounds__(256) void transpose_bf16(const u16* __restrict__ src,
                                                      u16* __restrict__ dst,
                                                      int srows, int scols) {
    __shared__ u16 t[64][72];
    int r0 = blockIdx.y * 64, c0 = blockIdx.x * 64;
    int tid = threadIdx.x;
    #pragma unroll
    for (int p = 0; p < 2; p++) {
        int q = p * 256 + tid;
        int r = q >> 3, c8 = q & 7;
        int4 v = *(reinterpret_cast<const int4*>(src + (size_t)(r0 + r) * scols + c0) + c8);
        const u16* u = reinterpret_cast<const u16*>(&v);
        #pragma unroll
        for (int k = 0; k < 8; k++) t[c8 * 8 + k][r] = u[k];
    }
    __syncthreads();
    #pragma unroll
    for (int p = 0; p < 2; p++) {
        int q = p * 256 + tid;
        int rr = q >> 3, cc = q & 7;
        *reinterpret_cast<int4*>(dst + (size_t)(c0 + rr) * srows + r0 + cc * 8) =
            *reinterpret_cast<const int4*>(&t[rr][cc * 8]);
    }
}

// ---------------- LN kernels ----------------
__global__ __launch_bounds__(256) void ln_y_k(const float* __restrict__ y2, const float* __restrict__ mn,
                                              const float* __restrict__ g, const float* __restrict__ b,
                                              u16* __restrict__ zb) {
    __shared__ float red[4];
    int r = blockIdx.x, tid = threadIdx.x;
    float4 a = reinterpret_cast<const float4*>(y2 + (size_t)r * 1024)[tid];
    float4 c = reinterpret_cast<const float4*>(mn + (size_t)r * 1024)[tid];
    float4 v; v.x = a.x + c.x; v.y = a.y + c.y; v.z = a.z + c.z; v.w = a.w + c.w;
    float s  = v.x + v.y + v.z + v.w;
    float sq = v.x * v.x + v.y * v.y + v.z * v.z + v.w * v.w;
    s  = blk_sum(s, red);
    sq = blk_sum(sq, red);
    float mu = s * (1.0f / 1024.0f);
    float rs = rsqrtf(sq * (1.0f / 1024.0f) - mu * mu + LN_EPS);
    float4 gg = reinterpret_cast<const float4*>(g)[tid];
    float4 bb = reinterpret_cast<const float4*>(b)[tid];
    ushort4 o;
    o.x = f2bf((v.x - mu) * rs * gg.x + bb.x);
    o.y = f2bf((v.y - mu) * rs * gg.y + bb.y);
    o.z = f2bf((v.z - mu) * rs * gg.z + bb.z);
    o.w = f2bf((v.w - mu) * rs * gg.w + bb.w);
    reinterpret_cast<ushort4*>(zb + (size_t)r * 1024)[tid] = o;
}

__global__ __launch_bounds__(256) void ln_dot_k(const float* __restrict__ h, const float* __restrict__ g,
                                                const float* __restrict__ b, const float* __restrict__ kd,
                                                const float* __restrict__ kdb, float* __restrict__ out) {
    __shared__ float red[4];
    int r = blockIdx.x, tid = threadIdx.x;
    float4 v = reinterpret_cast<const float4*>(h + (size_t)r * 1024)[tid];
    float s  = v.x + v.y + v.z + v.w;
    float sq = v.x * v.x + v.y * v.y + v.z * v.z + v.w * v.w;
    s  = blk_sum(s, red);
    sq = blk_sum(sq, red);
    float mu = s * (1.0f / 1024.0f);
    float rs = rsqrtf(sq * (1.0f / 1024.0f) - mu * mu + LN_EPS);
    float4 gg = reinterpret_cast<const float4*>(g)[tid];
    float4 bb = reinterpret_cast<const float4*>(b)[tid];
    float4 kk = reinterpret_cast<const float4*>(kd)[tid];
    float part = ((v.x - mu) * rs * gg.x + bb.x) * kk.x
               + ((v.y - mu) * rs * gg.y + bb.y) * kk.y
               + ((v.z - mu) * rs * gg.z + bb.z) * kk.z
               + ((v.w - mu) * rs * gg.w + bb.w) * kk.w;
    part = blk_sum(part, red);
    if (tid == 0) out[r] = 1.0f / (1.0f + __expf(-(part + kdb[0])));
}

// ---------------- launch ----------------
extern "C" void kernel_launch(void* const* d_in, const int* in_sizes, int n_in,
                              void* d_out, int out_size, void* d_ws, size_t ws_size,
                              hipStream_t stream) {
    (void)in_sizes; (void)n_in; (void)out_size; (void)ws_size;
    const float* x    = (const float*)d_in[0];
    const float* Wq   = (const float*)d_in[2];
    const float* Wk   = (const float*)d_in[3];
    const float* Wv   = (const float*)d_in[4];
    const float* Wo   = (const float*)d_in[5];
    const float* fc1w = (const float*)d_in[6];
    const float* fc1b = (const float*)d_in[7];
    const float* kaw  = (const float*)d_in[8];
    const float* kab  = (const float*)d_in[9];
    const float* kdw  = (const float*)d_in[10];
    const float* kdb  = (const float*)d_in[11];
    const float* lyg  = (const float*)d_in[12];
    const float* lyb  = (const float*)d_in[13];
    const float* lkg  = (const float*)d_in[14];
    const float* lkb  = (const float*)d_in[15];

    float* out0 = (float*)d_out;
    float* aw   = out0 + 8192;

    char* base = (char*)d_ws;
    size_t off = 0;
    auto alloc = [&](size_t bytes) -> char* {
        char* p = base + off;
        off += (bytes + 255) & ~(size_t)255;
        return p;
    };
    const size_t NM = 8192ULL * 1024ULL;           // 8,388,608
    u16*   ST   = (u16*)alloc(8192ULL * 8192ULL * 2);   // 128MB; first 64MB doubles as Sf
    float* Sf   = (float*)ST;                           // 2048 x 8192 fp32 chunk
    u16*   xh   = (u16*)alloc(NM * 2);
    u16*   xl   = (u16*)alloc(NM * 2);
    u16*   qh   = (u16*)alloc(NM * 2);
    u16*   ql   = (u16*)alloc(NM * 2);
    u16*   kh   = (u16*)alloc(NM * 2);
    u16*   kl   = (u16*)alloc(NM * 2);
    u16*   Vb   = (u16*)alloc(NM * 2);
    u16*   Vt   = (u16*)alloc(NM * 2);
    u16*   dbuf = (u16*)alloc(NM * 2);                  // later reused as zb
    u16*   yb   = (u16*)alloc(NM * 2);
    float* mn   = (float*)alloc(NM * 4);
    float* y    = (float*)alloc(NM * 4);                // later reused as h
    float* y2   = (float*)alloc(NM * 4);
    u16*   Wqh  = (u16*)alloc(1048576ULL * 2);
    u16*   Wql  = (u16*)alloc(1048576ULL * 2);
    u16*   Wkh  = (u16*)alloc(1048576ULL * 2);
    u16*   Wkl  = (u16*)alloc(1048576ULL * 2);
    u16*   Wvb  = (u16*)alloc(1048576ULL * 2);
    u16*   Wob  = (u16*)alloc(1048576ULL * 2);
    u16*   fwb  = (u16*)alloc(1048576ULL * 2);
    u16*   kwb  = (u16*)alloc(1048576ULL * 2);
    u16*   zb   = dbuf;
    float* hbuf = y;

    // 1) converts / splits
    split_k<<<4096, 256, 0, stream>>>(x, xh, xl);
    split_k<<<512, 256, 0, stream>>>(Wq, Wqh, Wql);
    split_k<<<512, 256, 0, stream>>>(Wk, Wkh, Wkl);
    cvt_k<<<512, 256, 0, stream>>>(Wv, Wvb);
    cvt_k<<<512, 256, 0, stream>>>(Wo, Wob);
    cvt_k<<<512, 256, 0, stream>>>(fc1w, fwb);
    cvt_k<<<512, 256, 0, stream>>>(kaw, kwb);

    // 2) mn = relu(d1@fc1^T+b) + relu(d2@..) + relu(d3@..); tail rows = x
    diff_k<<<8192, 256, 0, stream>>>(x, dbuf, 1);
    gemm_k<false, 1><<<dim3(8, 64), 256, 0, stream>>>(dbuf, nullptr, fwb, nullptr,
        mn, nullptr, nullptr, fc1b, 8192, 1024, 1024, 1024, 1.0f);
    diff_k<<<8192, 256, 0, stream>>>(x, dbuf, 2);
    gemm_k<false, 2><<<dim3(8, 64), 256, 0, stream>>>(dbuf, nullptr, fwb, nullptr,
        mn, nullptr, nullptr, fc1b, 8192, 1024, 1024, 1024, 1.0f);
    diff_k<<<8192, 256, 0, stream>>>(x, dbuf, 4);
    gemm_k<false, 2><<<dim3(8, 64), 256, 0, stream>>>(dbuf, nullptr, fwb, nullptr,
        mn, nullptr, nullptr, fc1b, 8192, 1024, 1024, 1024, 1.0f);
    tail_k<<<16, 256, 0, stream>>>(x, mn);

    // 3) Q (split, x0.06), K (split), V (plain)
    gemm_k<true, 4><<<dim3(8, 64), 256, 0, stream>>>(xh, xl, Wqh, Wql,
        nullptr, qh, ql, nullptr, 8192, 1024, 1024, 1024, 0.06f);
    gemm_k<true, 4><<<dim3(8, 64), 256, 0, stream>>>(xh, xl, Wkh, Wkl,
        nullptr, kh, kl, nullptr, 8192, 1024, 1024, 1024, 1.0f);
    gemm_k<false, 3><<<dim3(8, 64), 256, 0, stream>>>(xh, nullptr, Wvb, nullptr,
        nullptr, Vb, nullptr, nullptr, 8192, 1024, 1024, 1024, 1.0f);
    transpose_bf16<<<dim3(16, 128), 256, 0, stream>>>(Vb, Vt, 8192, 1024);

    // 4) logits (split, fp32) + softmax, 4 chunks of 2048 rows; aw -> d_out
    for (int c = 0; c < 4; ++c) {
        gemm_k<true, 0><<<dim3(64, 16), 256, 0, stream>>>(
            qh + (size_t)c * 2048 * 1024, ql + (size_t)c * 2048 * 1024, kh, kl,
            Sf, nullptr, nullptr, nullptr, 2048, 8192, 1024, 8192, 1.0f);
        softmax_k<<<2048, 256, 0, stream>>>(Sf, aw, c * 2048);
    }

    // 5) ST = aw^T (bf16), y = ST @ Vt^T  (== aw^T @ V)
    transpose_f32_bf16<<<dim3(128, 128), 256, 0, stream>>>(aw, ST);
    gemm_k<false, 0><<<dim3(8, 64), 256, 0, stream>>>(ST, nullptr, Vt, nullptr,
        y, nullptr, nullptr, nullptr, 8192, 1024, 8192, 1024, 1.0f);

    // 6) y2 = y @ Wo^T ; z = LN(y2+mn) ; h = relu(z@ka^T+b) ; out = sigmoid(LN(h)@kd^T+kdb)
    cvt_k<<<4096, 256, 0, stream>>>(y, yb);
    gemm_k<false, 0><<<dim3(8, 64), 256, 0, stream>>>(yb, nullptr, Wob, nullptr,
        y2, nullptr, nullptr, nullptr, 8192, 1024, 1024, 1024, 1.0f);
    ln_y_k<<<8192, 256, 0, stream>>>(y2, mn, lyg, lyb, zb);
    gemm_k<false, 1><<<dim3(8, 64), 256, 0, stream>>>(zb, nullptr, kwb, nullptr,
        hbuf, nullptr, nullptr, kab, 8192, 1024, 1024, 1024, 1.0f);
    ln_dot_k<<<8192, 256, 0, stream>>>(hbuf, lkg, lkb, kdw, kdb, out0);
}

// Round 3
// 1169.647 us; speedup vs baseline: 1.1347x; 1.1175x over previous
//
#include <hip/hip_runtime.h>
#include <cstdint>
#include <cstddef>

typedef unsigned short u16;
typedef short bf16x8 __attribute__((ext_vector_type(8)));
typedef float f32x4 __attribute__((ext_vector_type(4)));

#define LN_EPS 1e-6f

// async global->LDS, 16B per lane; LDS dest is wave-uniform base + lane*16
#define GLD16(gsrc, ldst) \
    __builtin_amdgcn_global_load_lds( \
        (const __attribute__((address_space(1))) void*)(gsrc), \
        (__attribute__((address_space(3))) void*)(ldst), 16, 0, 0)

__device__ inline u16 f2bf(float f) {
    uint32_t x = __float_as_uint(f);
    uint32_t r = (x + 0x7fffu + ((x >> 16) & 1u)) >> 16;   // RNE
    return (u16)r;
}
__device__ inline float bf2f(u16 u) { return __uint_as_float(((uint32_t)u) << 16); }

// ---------------- block reductions (256 threads = 4 waves) ----------------
__device__ inline float blk_sum(float v, float* s) {
    #pragma unroll
    for (int o = 32; o > 0; o >>= 1) v += __shfl_xor(v, o);
    __syncthreads();
    if ((threadIdx.x & 63) == 0) s[threadIdx.x >> 6] = v;
    __syncthreads();
    return s[0] + s[1] + s[2] + s[3];
}
__device__ inline float blk_max(float v, float* s) {
    #pragma unroll
    for (int o = 32; o > 0; o >>= 1) v = fmaxf(v, __shfl_xor(v, o));
    __syncthreads();
    if ((threadIdx.x & 63) == 0) s[threadIdx.x >> 6] = v;
    __syncthreads();
    return fmaxf(fmaxf(s[0], s[1]), fmaxf(s[2], s[3]));
}

// =====================================================================
// 8-phase 256x256 GEMM (plain-HIP port of the m201 template).
// C[m][n] = sum_k A[m][k]*B[n][k], both row-major k-contiguous, f32 out.
// BK=64 staged as 2 k-halves (256x32 each) per tensor; double-buffered.
// Counted vmcnt(4) checkpoints (phases 2,4) — never drain-0 mid-loop.
// LDS bank swizzle: slot ^= (row>>1)&3 (16B slots), applied on the
// global SOURCE col for staging (linear global_load_lds dest) and on the
// ds_read address — both sides, same involution (rule #21).
// Grid: (N/256, M/256, Z); Z = split-K slices (A,B advanced by z*K elems,
// C advanced by z*zCstride floats). Requires gridDim.x*gridDim.y % 8 == 0.
// =====================================================================
__global__ __launch_bounds__(512, 2) void gemm8_k(
    const u16* __restrict__ A, const u16* __restrict__ B, float* __restrict__ Cf,
    int lda, int ldb, int ldc, int K, size_t zCstride, float scale)
{
    __shared__ u16 lds[65536];   // 128 KiB: [buf][A/B][kh][256 rows][32 cols]

    const int tid  = threadIdx.x;
    const int lane = tid & 63, wid = tid >> 6;
    const int wr = wid >> 2, wc = wid & 3;        // 2x4 waves, each 128x64 of C
    const int fr = lane & 15, fg = lane >> 4;

    const int gx  = gridDim.x, nwg = gx * gridDim.y;
    const int bid = blockIdx.y * gx + blockIdx.x;
    const int wg  = (bid & 7) * (nwg >> 3) + (bid >> 3);   // XCD-contiguous
    const int n0  = (wg % gx) * 256, m0 = (wg / gx) * 256;

    const u16* Ab = A + (size_t)blockIdx.z * K;
    const u16* Bb = B + (size_t)blockIdx.z * K;
    float*      C = Cf + (size_t)blockIdx.z * zCstride;

    // staging geometry: thread covers row sr (and sr+128), 16B slot (tid&3)
    const int sr = tid >> 2;
    const int kb = ((tid & 3) ^ ((sr >> 1) & 3)) * 8;   // pre-swizzled col (elems)

    f32x4 acc[8][4];
    {
        f32x4 z = {0.f, 0.f, 0.f, 0.f};
        #pragma unroll
        for (int m = 0; m < 8; m++)
            #pragma unroll
            for (int n = 0; n < 4; n++) acc[m][n] = z;
    }

    const int NT = K >> 6;

    auto STAGE = [&](int buf, int isB, int kh, int kt) {
        const u16* src = isB ? Bb : Ab;
        const int  ld  = isB ? ldb : lda;
        const int  rb  = isB ? n0 : m0;
        const int  k0  = kt * 64 + kh * 32 + kb;
        u16* dst = &lds[buf * 32768 + isB * 16384 + kh * 8192 + tid * 8];
        GLD16(src + (size_t)(rb + sr) * ld + k0, dst);
        GLD16(src + (size_t)(rb + 128 + sr) * ld + k0, dst + 4096);
    };

    // per-lane read bases (u16 units); ((row>>1)&3) == ((fr>>1)&3) here
    const int swz   = (fg ^ ((fr >> 1) & 3)) * 8;
    const int baseA = (wr * 128 + fr) * 32 + swz;          // +m*512 +ks*8192 +buf*32768
    const int baseB = 16384 + (wc * 64 + fr) * 32 + swz;   // +n*512 +ks*8192 +buf*32768

    // prologue: stage tile 0 halves in order A-kh0, B-kh0, A-kh1, B-kh1
    STAGE(0, 0, 0, 0); STAGE(0, 1, 0, 0); STAGE(0, 0, 1, 0); STAGE(0, 1, 1, 0);
    asm volatile("s_waitcnt vmcnt(4)" ::: "memory");       // kh0 pair landed
    __builtin_amdgcn_s_barrier();

    bf16x8 af[4], bv[4];

    for (int t = 0; t < NT; ++t) {
        const int  aO  = (t & 1) * 32768;
        const int  nxt = (t & 1) ^ 1;
        const bool pre = (t + 1 < NT);

        // ---- phase 1: (ms=0, ks=0) -- 8 ds_read + stage A-kh0(t+1)
        #pragma unroll
        for (int m = 0; m < 4; m++) af[m] = *(const bf16x8*)&lds[baseA + aO + m * 512];
        #pragma unroll
        for (int n = 0; n < 4; n++) bv[n] = *(const bf16x8*)&lds[baseB + aO + n * 512];
        if (pre) STAGE(nxt, 0, 0, t + 1);
        __builtin_amdgcn_s_barrier();
        asm volatile("s_waitcnt lgkmcnt(0)" ::: "memory");
        __builtin_amdgcn_sched_barrier(0);
        __builtin_amdgcn_s_setprio(1);
        #pragma unroll
        for (int m = 0; m < 4; m++)
            #pragma unroll
            for (int n = 0; n < 4; n++)
                acc[m][n] = __builtin_amdgcn_mfma_f32_16x16x32_bf16(af[m], bv[n], acc[m][n], 0, 0, 0);
        __builtin_amdgcn_s_setprio(0);
        __builtin_amdgcn_s_barrier();

        // ---- phase 2: (ms=1, ks=0) -- 4 ds_read + stage B-kh0(t+1); ckpt kh1(t)
        #pragma unroll
        for (int m = 0; m < 4; m++) af[m] = *(const bf16x8*)&lds[baseA + aO + (4 + m) * 512];
        if (pre) STAGE(nxt, 1, 0, t + 1);
        __builtin_amdgcn_s_barrier();
        asm volatile("s_waitcnt lgkmcnt(0)" ::: "memory");
        __builtin_amdgcn_sched_barrier(0);
        __builtin_amdgcn_s_setprio(1);
        #pragma unroll
        for (int m = 0; m < 4; m++)
            #pragma unroll
            for (int n = 0; n < 4; n++)
                acc[4 + m][n] = __builtin_amdgcn_mfma_f32_16x16x32_bf16(af[m], bv[n], acc[4 + m][n], 0, 0, 0);
        __builtin_amdgcn_s_setprio(0);
        if (pre) { asm volatile("s_waitcnt vmcnt(4)" ::: "memory"); }
        else     { asm volatile("s_waitcnt vmcnt(0)" ::: "memory"); }
        __builtin_amdgcn_sched_barrier(0);
        __builtin_amdgcn_s_barrier();

        // ---- phase 3: (ms=0, ks=1) -- 8 ds_read + stage A-kh1(t+1)
        #pragma unroll
        for (int m = 0; m < 4; m++) af[m] = *(const bf16x8*)&lds[baseA + aO + 8192 + m * 512];
        #pragma unroll
        for (int n = 0; n < 4; n++) bv[n] = *(const bf16x8*)&lds[baseB + aO + 8192 + n * 512];
        if (pre) STAGE(nxt, 0, 1, t + 1);
        __builtin_amdgcn_s_barrier();
        asm volatile("s_waitcnt lgkmcnt(0)" ::: "memory");
        __builtin_amdgcn_sched_barrier(0);
        __builtin_amdgcn_s_setprio(1);
        #pragma unroll
        for (int m = 0; m < 4; m++)
            #pragma unroll
            for (int n = 0; n < 4; n++)
                acc[m][n] = __builtin_amdgcn_mfma_f32_16x16x32_bf16(af[m], bv[n], acc[m][n], 0, 0, 0);
        __builtin_amdgcn_s_setprio(0);
        __builtin_amdgcn_s_barrier();

        // ---- phase 4: (ms=1, ks=1) -- 4 ds_read + stage B-kh1(t+1); ckpt kh0(t+1)
        #pragma unroll
        for (int m = 0; m < 4; m++) af[m] = *(const bf16x8*)&lds[baseA + aO + 8192 + (4 + m) * 512];
        if (pre) STAGE(nxt, 1, 1, t + 1);
        __builtin_amdgcn_s_barrier();
        asm volatile("s_waitcnt lgkmcnt(0)" ::: "memory");
        __builtin_amdgcn_sched_barrier(0);
        __builtin_amdgcn_s_setprio(1);
        #pragma unroll
        for (int m = 0; m < 4; m++)
            #pragma unroll
            for (int n = 0; n < 4; n++)
                acc[4 + m][n] = __builtin_amdgcn_mfma_f32_16x16x32_bf16(af[m], bv[n], acc[4 + m][n], 0, 0, 0);
        __builtin_amdgcn_s_setprio(0);
        if (pre) { asm volatile("s_waitcnt vmcnt(4)" ::: "memory"); }
        __builtin_amdgcn_sched_barrier(0);
        __builtin_amdgcn_s_barrier();
    }

    // epilogue: D layout col = lane&15, row = (lane>>4)*4 + reg [HW-verified]
    #pragma unroll
    for (int m = 0; m < 8; m++)
        #pragma unroll
        for (int n = 0; n < 4; n++)
            #pragma unroll
            for (int r = 0; r < 4; r++) {
                int row = m0 + wr * 128 + m * 16 + fg * 4 + r;
                int col = n0 + wc * 64 + n * 16 + fr;
                C[(size_t)row * ldc + col] = acc[m][n][r] * scale;
            }
}

// ---------------- old 128^2 2-phase GEMM (small GEMMs / split projections)
// MODE: 0 = f32 store, 1 = f32 relu(acc+bias), 2 = f32 += relu(acc+bias),
//       3 = bf16 store, 4 = bf16 split hi/lo store
template<bool SPLIT, int MODE>
__global__ __launch_bounds__(256) void gemm_k(
    const u16* __restrict__ A, const u16* __restrict__ Al,
    const u16* __restrict__ B, const u16* __restrict__ Bl,
    float* __restrict__ Cf, u16* __restrict__ Cb, u16* __restrict__ Cb2,
    const float* __restrict__ bias,
    int M, int N, int K, int ldc, float scale)
{
    __shared__ u16 sA[128 * 32];
    __shared__ u16 sB[128 * 32];
    __shared__ u16 sAl[SPLIT ? 128 * 32 : 8];
    __shared__ u16 sBl[SPLIT ? 128 * 32 : 8];

    const int tid  = threadIdx.x;
    const int lane = tid & 63;
    const int wid  = tid >> 6;
    const int wr = wid >> 1, wc = wid & 1;
    const int fr = lane & 15;
    const int fg = lane >> 4;

    const int gx = gridDim.x;
    const int nwg = gx * gridDim.y;
    const int bid = blockIdx.y * gx + blockIdx.x;
    const int wg  = (bid & 7) * (nwg >> 3) + (bid >> 3);
    const int m0 = (wg / gx) * 128, n0 = (wg % gx) * 128;

    f32x4 acc[4][4];
    {
        f32x4 z = {0.f, 0.f, 0.f, 0.f};
        #pragma unroll
        for (int i = 0; i < 4; i++)
            #pragma unroll
            for (int j = 0; j < 4; j++) acc[i][j] = z;
    }

    for (int k0 = 0; k0 < K; k0 += 32) {
        #pragma unroll
        for (int c2 = 0; c2 < 2; ++c2) {
            int c    = wid * 2 + c2;
            int boff = c * 1024 + lane * 16;
            int row  = boff >> 6;
            int kb   = (boff & 63) >> 1;
            size_t ga = (size_t)(m0 + row) * K + (k0 + kb);
            size_t gb = (size_t)(n0 + row) * K + (k0 + kb);
            GLD16(A + ga, &sA[c * 512]);
            GLD16(B + gb, &sB[c * 512]);
            if constexpr (SPLIT) {
                GLD16(Al + ga, &sAl[c * 512]);
                GLD16(Bl + gb, &sBl[c * 512]);
            }
        }
        __syncthreads();

        bf16x8 av[4], bv[4], avl[4], bvl[4];
        #pragma unroll
        for (int f = 0; f < 4; ++f) {
            av[f] = *reinterpret_cast<const bf16x8*>(&sA[(wr * 64 + f * 16 + fr) * 32 + fg * 8]);
            bv[f] = *reinterpret_cast<const bf16x8*>(&sB[(wc * 64 + f * 16 + fr) * 32 + fg * 8]);
            if constexpr (SPLIT) {
                avl[f] = *reinterpret_cast<const bf16x8*>(&sAl[(wr * 64 + f * 16 + fr) * 32 + fg * 8]);
                bvl[f] = *reinterpret_cast<const bf16x8*>(&sBl[(wc * 64 + f * 16 + fr) * 32 + fg * 8]);
            }
        }
        #pragma unroll
        for (int i = 0; i < 4; i++)
            #pragma unroll
            for (int j = 0; j < 4; j++) {
                acc[i][j] = __builtin_amdgcn_mfma_f32_16x16x32_bf16(av[i], bv[j], acc[i][j], 0, 0, 0);
                if constexpr (SPLIT) {
                    acc[i][j] = __builtin_amdgcn_mfma_f32_16x16x32_bf16(avl[i], bv[j], acc[i][j], 0, 0, 0);
                    acc[i][j] = __builtin_amdgcn_mfma_f32_16x16x32_bf16(av[i], bvl[j], acc[i][j], 0, 0, 0);
                }
            }
        __syncthreads();
    }

    #pragma unroll
    for (int i = 0; i < 4; i++)
        #pragma unroll
        for (int j = 0; j < 4; j++)
            #pragma unroll
            for (int r = 0; r < 4; r++) {
                int row = m0 + wr * 64 + i * 16 + fg * 4 + r;
                int col = n0 + wc * 64 + j * 16 + fr;
                float v = acc[i][j][r] * scale;
                size_t idx = (size_t)row * ldc + col;
                if (MODE == 0) {
                    Cf[idx] = v;
                } else if (MODE == 1) {
                    Cf[idx] = fmaxf(v + bias[col], 0.f);
                } else if (MODE == 2) {
                    Cf[idx] += fmaxf(v + bias[col], 0.f);
                } else if (MODE == 3) {
                    Cb[idx] = f2bf(v);
                } else {
                    u16 h = f2bf(v);
                    Cb[idx]  = h;
                    Cb2[idx] = f2bf(v - bf2f(h));
                }
            }
}

// ---------------- elementwise / converts ----------------
__global__ __launch_bounds__(256) void split_k(const float* __restrict__ s,
                                               u16* __restrict__ hi, u16* __restrict__ lo) {
    int i = blockIdx.x * 256 + threadIdx.x;
    const float4* sf = reinterpret_cast<const float4*>(s);
    float4 a = sf[2 * i], b = sf[2 * i + 1];
    float vals[8] = {a.x, a.y, a.z, a.w, b.x, b.y, b.z, b.w};
    union { u16 u[8]; int4 v; } th, tl;
    #pragma unroll
    for (int k = 0; k < 8; k++) {
        u16 h = f2bf(vals[k]);
        th.u[k] = h;
        tl.u[k] = f2bf(vals[k] - bf2f(h));
    }
    reinterpret_cast<int4*>(hi)[i] = th.v;
    reinterpret_cast<int4*>(lo)[i] = tl.v;
}

__global__ __launch_bounds__(256) void cvt_k(const float* __restrict__ s, u16* __restrict__ d) {
    int i = blockIdx.x * 256 + threadIdx.x;
    const float4* sf = reinterpret_cast<const float4*>(s);
    float4 a = sf[2 * i], b = sf[2 * i + 1];
    union { u16 u[8]; int4 v; } t;
    t.u[0] = f2bf(a.x); t.u[1] = f2bf(a.y); t.u[2] = f2bf(a.z); t.u[3] = f2bf(a.w);
    t.u[4] = f2bf(b.x); t.u[5] = f2bf(b.y); t.u[6] = f2bf(b.z); t.u[7] = f2bf(b.w);
    reinterpret_cast<int4*>(d)[i] = t.v;
}

// yb = bf16(y + y2)  (split-K PV reduction fused into the convert)
__global__ __launch_bounds__(256) void cvt2_k(const float* __restrict__ s0, const float* __restrict__ s1,
                                              u16* __restrict__ d) {
    int i = blockIdx.x * 256 + threadIdx.x;
    const float4* f0 = reinterpret_cast<const float4*>(s0);
    const float4* f1 = reinterpret_cast<const float4*>(s1);
    float4 a = f0[2 * i], b = f0[2 * i + 1];
    float4 c = f1[2 * i], e = f1[2 * i + 1];
    union { u16 u[8]; int4 v; } t;
    t.u[0] = f2bf(a.x + c.x); t.u[1] = f2bf(a.y + c.y);
    t.u[2] = f2bf(a.z + c.z); t.u[3] = f2bf(a.w + c.w);
    t.u[4] = f2bf(b.x + e.x); t.u[5] = f2bf(b.y + e.y);
    t.u[6] = f2bf(b.z + e.z); t.u[7] = f2bf(b.w + e.w);
    reinterpret_cast<int4*>(d)[i] = t.v;
}

// dst rows = [s0 | s1 | s2] (each 8192x1024 bf16 -> 8192x3072)
__global__ __launch_bounds__(256) void cat3_k(const u16* __restrict__ s0, const u16* __restrict__ s1,
                                              const u16* __restrict__ s2, u16* __restrict__ dst) {
    int i = blockIdx.x * 256 + threadIdx.x;     // int4-chunk id: 8192 rows x 128 chunks
    int r = i >> 7, c8 = i & 127;
    const int4* p0 = reinterpret_cast<const int4*>(s0 + (size_t)r * 1024);
    const int4* p1 = reinterpret_cast<const int4*>(s1 + (size_t)r * 1024);
    const int4* p2 = reinterpret_cast<const int4*>(s2 + (size_t)r * 1024);
    int4* d = reinterpret_cast<int4*>(dst + (size_t)r * 3072);
    d[c8]       = p0[c8];
    d[c8 + 128] = p1[c8];
    d[c8 + 256] = p2[c8];
}

// dbuf[i][:] = bf16(|x[i+shift][:] - x[i][:]|) for i<8188, else 0
__global__ __launch_bounds__(256) void diff_k(const float* __restrict__ x, u16* __restrict__ d, int shift) {
    int i4 = blockIdx.x * 256 + threadIdx.x;
    int row = i4 >> 8;
    const float4* xf = reinterpret_cast<const float4*>(x);
    ushort4 o;
    if (row < 8188) {
        float4 a = xf[i4 + (shift << 8)];
        float4 b = xf[i4];
        o.x = f2bf(fabsf(a.x - b.x));
        o.y = f2bf(fabsf(a.y - b.y));
        o.z = f2bf(fabsf(a.z - b.z));
        o.w = f2bf(fabsf(a.w - b.w));
    } else {
        o.x = o.y = o.z = o.w = 0;
    }
    reinterpret_cast<ushort4*>(d)[i4] = o;
}

__global__ __launch_bounds__(256) void tail_k(const float* __restrict__ x, float* __restrict__ mn) {
    int i = blockIdx.x * 256 + threadIdx.x;
    mn[8188 * 1024 + i] = x[8188 * 1024 + i];
}

// ---------------- softmax over a row of 8192 fp32 ----------------
__global__ __launch_bounds__(256) void softmax_k(const float* __restrict__ S,
                                                 float* __restrict__ aw, int row0) {
    __shared__ float red[4];
    int r = blockIdx.x, tid = threadIdx.x;
    const float4* src = reinterpret_cast<const float4*>(S + (size_t)r * 8192);
    float4 xv[8];
    float mx = -1e30f;
    #pragma unroll
    for (int j = 0; j < 8; j++) {
        xv[j] = src[tid + 256 * j];
        mx = fmaxf(mx, fmaxf(fmaxf(xv[j].x, xv[j].y), fmaxf(xv[j].z, xv[j].w)));
    }
    mx = blk_max(mx, red);
    float sum = 0.f;
    #pragma unroll
    for (int j = 0; j < 8; j++) {
        xv[j].x = __expf(xv[j].x - mx); sum += xv[j].x;
        xv[j].y = __expf(xv[j].y - mx); sum += xv[j].y;
        xv[j].z = __expf(xv[j].z - mx); sum += xv[j].z;
        xv[j].w = __expf(xv[j].w - mx); sum += xv[j].w;
    }
    sum = blk_sum(sum, red);
    float inv = 1.0f / sum;
    float4* dst = reinterpret_cast<float4*>(aw + (size_t)(row0 + r) * 8192);
    #pragma unroll
    for (int j = 0; j < 8; j++) {
        float4 o;
        o.x = xv[j].x * inv; o.y = xv[j].y * inv; o.z = xv[j].z * inv; o.w = xv[j].w * inv;
        dst[tid + 256 * j] = o;
    }
}

// ---------------- transposes (64x64 tiles) ----------------
__global__ __launch_bounds__(256) void transpose_f32_bf16(const float* __restrict__ src,
                                                          u16* __restrict__ dst) {
    __shared__ u16 t[64][72];
    int r0 = blockIdx.y * 64, c0 = blockIdx.x * 64;
    int tid = threadIdx.x;
    #pragma unroll
    for (int p = 0; p < 4; p++) {
        int q = p * 256 + tid;
        int r = q >> 4, c4 = q & 15;
        float4 v = *(reinterpret_cast<const float4*>(src + (size_t)(r0 + r) * 8192 + c0) + c4);
        t[c4 * 4 + 0][r] = f2bf(v.x);
        t[c4 * 4 + 1][r] = f2bf(v.y);
        t[c4 * 4 + 2][r] = f2bf(v.z);
        t[c4 * 4 + 3][r] = f2bf(v.w);
    }
    __syncthreads();
    #pragma unroll
    for (int p = 0; p < 2; p++) {
        int q = p * 256 + tid;
        int rr = q >> 3, cc = q & 7;
        *reinterpret_cast<int4*>(dst + (size_t)(c0 + rr) * 8192 + r0 + cc * 8) =
            *reinterpret_cast<const int4*>(&t[rr][cc * 8]);
    }
}

__global__ __launch_bounds__(256) void transpose_bf16(const u16* __restrict__ src,
                                                      u16* __restrict__ dst,
                                                      int srows, int scols) {
    __shared__ u16 t[64][72];
    int r0 = blockIdx.y * 64, c0 = blockIdx.x * 64;
    int tid = threadIdx.x;
    #pragma unroll
    for (int p = 0; p < 2; p++) {
        int q = p * 256 + tid;
        int r = q >> 3, c8 = q & 7;
        int4 v = *(reinterpret_cast<const int4*>(src + (size_t)(r0 + r) * scols + c0) + c8);
        const u16* u = reinterpret_cast<const u16*>(&v);
        #pragma unroll
        for (int k = 0; k < 8; k++) t[c8 * 8 + k][r] = u[k];
    }
    __syncthreads();
    #pragma unroll
    for (int p = 0; p < 2; p++) {
        int q = p * 256 + tid;
        int rr = q >> 3, cc = q & 7;
        *reinterpret_cast<int4*>(dst + (size_t)(c0 + rr) * srows + r0 + cc * 8) =
            *reinterpret_cast<const int4*>(&t[rr][cc * 8]);
    }
}

// ---------------- LN kernels ----------------
__global__ __launch_bounds__(256) void ln_y_k(const float* __restrict__ y2, const float* __restrict__ mn,
                                              const float* __restrict__ g, const float* __restrict__ b,
                                              u16* __restrict__ zb) {
    __shared__ float red[4];
    int r = blockIdx.x, tid = threadIdx.x;
    float4 a = reinterpret_cast<const float4*>(y2 + (size_t)r * 1024)[tid];
    float4 c = reinterpret_cast<const float4*>(mn + (size_t)r * 1024)[tid];
    float4 v; v.x = a.x + c.x; v.y = a.y + c.y; v.z = a.z + c.z; v.w = a.w + c.w;
    float s  = v.x + v.y + v.z + v.w;
    float sq = v.x * v.x + v.y * v.y + v.z * v.z + v.w * v.w;
    s  = blk_sum(s, red);
    sq = blk_sum(sq, red);
    float mu = s * (1.0f / 1024.0f);
    float rs = rsqrtf(sq * (1.0f / 1024.0f) - mu * mu + LN_EPS);
    float4 gg = reinterpret_cast<const float4*>(g)[tid];
    float4 bb = reinterpret_cast<const float4*>(b)[tid];
    ushort4 o;
    o.x = f2bf((v.x - mu) * rs * gg.x + bb.x);
    o.y = f2bf((v.y - mu) * rs * gg.y + bb.y);
    o.z = f2bf((v.z - mu) * rs * gg.z + bb.z);
    o.w = f2bf((v.w - mu) * rs * gg.w + bb.w);
    reinterpret_cast<ushort4*>(zb + (size_t)r * 1024)[tid] = o;
}

__global__ __launch_bounds__(256) void ln_dot_k(const float* __restrict__ h, const float* __restrict__ g,
                                                const float* __restrict__ b, const float* __restrict__ kd,
                                                const float* __restrict__ kdb, float* __restrict__ out) {
    __shared__ float red[4];
    int r = blockIdx.x, tid = threadIdx.x;
    float4 v = reinterpret_cast<const float4*>(h + (size_t)r * 1024)[tid];
    float s  = v.x + v.y + v.z + v.w;
    float sq = v.x * v.x + v.y * v.y + v.z * v.z + v.w * v.w;
    s  = blk_sum(s, red);
    sq = blk_sum(sq, red);
    float mu = s * (1.0f / 1024.0f);
    float rs = rsqrtf(sq * (1.0f / 1024.0f) - mu * mu + LN_EPS);
    float4 gg = reinterpret_cast<const float4*>(g)[tid];
    float4 bb = reinterpret_cast<const float4*>(b)[tid];
    float4 kk = reinterpret_cast<const float4*>(kd)[tid];
    float part = ((v.x - mu) * rs * gg.x + bb.x) * kk.x
               + ((v.y - mu) * rs * gg.y + bb.y) * kk.y
               + ((v.z - mu) * rs * gg.z + bb.z) * kk.z
               + ((v.w - mu) * rs * gg.w + bb.w) * kk.w;
    part = blk_sum(part, red);
    if (tid == 0) out[r] = 1.0f / (1.0f + __expf(-(part + kdb[0])));
}

// ---------------- launch ----------------
extern "C" void kernel_launch(void* const* d_in, const int* in_sizes, int n_in,
                              void* d_out, int out_size, void* d_ws, size_t ws_size,
                              hipStream_t stream) {
    (void)in_sizes; (void)n_in; (void)out_size; (void)ws_size;
    const float* x    = (const float*)d_in[0];
    const float* Wq   = (const float*)d_in[2];
    const float* Wk   = (const float*)d_in[3];
    const float* Wv   = (const float*)d_in[4];
    const float* Wo   = (const float*)d_in[5];
    const float* fc1w = (const float*)d_in[6];
    const float* fc1b = (const float*)d_in[7];
    const float* kaw  = (const float*)d_in[8];
    const float* kab  = (const float*)d_in[9];
    const float* kdw  = (const float*)d_in[10];
    const float* kdb  = (const float*)d_in[11];
    const float* lyg  = (const float*)d_in[12];
    const float* lyb  = (const float*)d_in[13];
    const float* lkg  = (const float*)d_in[14];
    const float* lkb  = (const float*)d_in[15];

    float* out0 = (float*)d_out;
    float* aw   = out0 + 8192;

    char* base = (char*)d_ws;
    size_t off = 0;
    auto alloc = [&](size_t bytes) -> char* {
        char* p = base + off;
        off += (bytes + 255) & ~(size_t)255;
        return p;
    };
    const size_t NM = 8192ULL * 1024ULL;
    u16*   ST   = (u16*)alloc(8192ULL * 8192ULL * 2);   // 128MB; first 64MB doubles as Sf
    float* Sf   = (float*)ST;
    u16*   xh   = (u16*)alloc(NM * 2);
    u16*   xl   = (u16*)alloc(NM * 2);
    u16*   qh   = (u16*)alloc(NM * 2);
    u16*   ql   = (u16*)alloc(NM * 2);
    u16*   kh   = (u16*)alloc(NM * 2);
    u16*   kl   = (u16*)alloc(NM * 2);
    u16*   Vb   = (u16*)alloc(NM * 2);
    u16*   Vt   = (u16*)alloc(NM * 2);
    u16*   dbuf = (u16*)alloc(NM * 2);                  // later reused as zb
    u16*   yb   = (u16*)alloc(NM * 2);
    float* mn   = (float*)alloc(NM * 4);
    float* y    = (float*)alloc(NM * 4);                // later reused as h; Qcat aliases y..y2
    float* y2   = (float*)alloc(NM * 4);                // y2 == y + NM (256B-aligned sizes)
    u16*   Wqh  = (u16*)alloc(1048576ULL * 2);
    u16*   Wql  = (u16*)alloc(1048576ULL * 2);
    u16*   Wkh  = (u16*)alloc(1048576ULL * 2);
    u16*   Wkl  = (u16*)alloc(1048576ULL * 2);
    u16*   Wvb  = (u16*)alloc(1048576ULL * 2);
    u16*   Wob  = (u16*)alloc(1048576ULL * 2);
    u16*   fwb  = (u16*)alloc(1048576ULL * 2);
    u16*   kwb  = (u16*)alloc(1048576ULL * 2);
    u16*   Kcat = (u16*)alloc(8192ULL * 3072ULL * 2);   // 48MB
    u16*   Qcat = (u16*)y;                              // 48MB alias over y+y2 (dead before PV)
    u16*   zb   = dbuf;
    float* hbuf = y;

    // 1) converts / splits
    split_k<<<4096, 256, 0, stream>>>(x, xh, xl);
    split_k<<<512, 256, 0, stream>>>(Wq, Wqh, Wql);
    split_k<<<512, 256, 0, stream>>>(Wk, Wkh, Wkl);
    cvt_k<<<512, 256, 0, stream>>>(Wv, Wvb);
    cvt_k<<<512, 256, 0, stream>>>(Wo, Wob);
    cvt_k<<<512, 256, 0, stream>>>(fc1w, fwb);
    cvt_k<<<512, 256, 0, stream>>>(kaw, kwb);

    // 2) mn branch
    diff_k<<<8192, 256, 0, stream>>>(x, dbuf, 1);
    gemm_k<false, 1><<<dim3(8, 64), 256, 0, stream>>>(dbuf, nullptr, fwb, nullptr,
        mn, nullptr, nullptr, fc1b, 8192, 1024, 1024, 1024, 1.0f);
    diff_k<<<8192, 256, 0, stream>>>(x, dbuf, 2);
    gemm_k<false, 2><<<dim3(8, 64), 256, 0, stream>>>(dbuf, nullptr, fwb, nullptr,
        mn, nullptr, nullptr, fc1b, 8192, 1024, 1024, 1024, 1.0f);
    diff_k<<<8192, 256, 0, stream>>>(x, dbuf, 4);
    gemm_k<false, 2><<<dim3(8, 64), 256, 0, stream>>>(dbuf, nullptr, fwb, nullptr,
        mn, nullptr, nullptr, fc1b, 8192, 1024, 1024, 1024, 1.0f);
    tail_k<<<16, 256, 0, stream>>>(x, mn);

    // 3) Q (split, x0.06), K (split), V (plain); build concat operands
    gemm_k<true, 4><<<dim3(8, 64), 256, 0, stream>>>(xh, xl, Wqh, Wql,
        nullptr, qh, ql, nullptr, 8192, 1024, 1024, 1024, 0.06f);
    gemm_k<true, 4><<<dim3(8, 64), 256, 0, stream>>>(xh, xl, Wkh, Wkl,
        nullptr, kh, kl, nullptr, 8192, 1024, 1024, 1024, 1.0f);
    gemm_k<false, 3><<<dim3(8, 64), 256, 0, stream>>>(xh, nullptr, Wvb, nullptr,
        nullptr, Vb, nullptr, nullptr, 8192, 1024, 1024, 1024, 1.0f);
    transpose_bf16<<<dim3(16, 128), 256, 0, stream>>>(Vb, Vt, 8192, 1024);
    cat3_k<<<4096, 256, 0, stream>>>(qh, ql, qh, Qcat);   // [Qh|Ql|Qh]
    cat3_k<<<4096, 256, 0, stream>>>(kh, kh, kl, Kcat);   // [Kh|Kh|Kl]

    // 4) logits via single K=3072 concat GEMM (== QhKh+QlKh+QhKl) + softmax
    for (int c = 0; c < 4; ++c) {
        gemm8_k<<<dim3(32, 8, 1), 512, 0, stream>>>(
            Qcat + (size_t)c * 2048 * 3072, Kcat, Sf, 3072, 3072, 8192, 3072, 0, 1.0f);
        softmax_k<<<2048, 256, 0, stream>>>(Sf, aw, c * 2048);
    }

    // 5) ST = aw^T (bf16); y/y2 = split-K halves of ST @ Vt^T  (== aw^T @ V)
    transpose_f32_bf16<<<dim3(128, 128), 256, 0, stream>>>(aw, ST);
    gemm8_k<<<dim3(4, 32, 2), 512, 0, stream>>>(
        ST, Vt, y, 8192, 8192, 1024, 4096, NM, 1.0f);
    cvt2_k<<<4096, 256, 0, stream>>>(y, y2, yb);

    // 6) head
    gemm_k<false, 0><<<dim3(8, 64), 256, 0, stream>>>(yb, nullptr, Wob, nullptr,
        y2, nullptr, nullptr, nullptr, 8192, 1024, 1024, 1024, 1.0f);
    ln_y_k<<<8192, 256, 0, stream>>>(y2, mn, lyg, lyb, zb);
    gemm_k<false, 1><<<dim3(8, 64), 256, 0, stream>>>(zb, nullptr, kwb, nullptr,
        hbuf, nullptr, nullptr, kab, 8192, 1024, 1024, 1024, 1.0f);
    ln_dot_k<<<8192, 256, 0, stream>>>(hbuf, lkg, lkb, kdw, kdb, out0);
}